// Round 2
// baseline (126.936 us; speedup 1.0000x reference)
//
#include <hip/hip_runtime.h>

#define NB   4
#define CIN  256
#define L    1024
#define NH   8
#define DH   32
#define COUT 512

typedef _Float16 half8 __attribute__((ext_vector_type(8)));
typedef _Float16 half4 __attribute__((ext_vector_type(4)));
typedef float    f32x4 __attribute__((ext_vector_type(4)));

// ---------------- kernel 0: prep — x (B,C,H,W) -> xT (B,L,C) f16 ; weights -> f16 ----------------
__global__ __launch_bounds__(256) void k_prep(const float* __restrict__ x, const float* __restrict__ wq,
                                              const float* __restrict__ wa, const float* __restrict__ wo,
                                              _Float16* __restrict__ xbT, _Float16* __restrict__ wqb,
                                              _Float16* __restrict__ wab, _Float16* __restrict__ wob) {
    int blk = blockIdx.x;
    if (blk < 16) {
        int t = blk * 256 + threadIdx.x;      // t = b*L + l
        int b = t >> 10;
        int l = t & (L - 1);
        const float* xp = x + (size_t)b * CIN * L + l;
        _Float16* op = xbT + (size_t)t * CIN;
        for (int c0 = 0; c0 < CIN; c0 += 8) {
            half8 v;
            #pragma unroll
            for (int j = 0; j < 8; ++j) v[j] = (_Float16)xp[(c0 + j) * L];
            *(half8*)(op + c0) = v;
        }
    } else {
        int i = (blk - 16) * 256 + threadIdx.x;
        if (i < 768 * 256) wqb[i] = (_Float16)wq[i];
        if (i < 256 * 256) { wab[i] = (_Float16)wa[i]; wob[i] = (_Float16)wo[i]; }
    }
}

// ---------------- kernel 1: QKV projection (MFMA), writes q(scaled)/k rows + v transposed ----------------
__global__ __launch_bounds__(256) void k_qkv(const _Float16* __restrict__ xbT, const _Float16* __restrict__ wqb,
                                             const float* __restrict__ bqkv,
                                             _Float16* __restrict__ qb, _Float16* __restrict__ kb,
                                             _Float16* __restrict__ vt) {
    int lane = threadIdx.x & 63, wv = threadIdx.x >> 6;
    int wid = blockIdx.x * 4 + wv;            // 12288 waves: b * (48 o-tiles) * (64 l-tiles)
    int b = wid / 3072; int rem = wid - b * 3072;
    int ot = rem >> 6, lt = rem & 63;
    int g = lane >> 4, q15 = lane & 15;
    const _Float16* Ap = wqb + (ot * 16 + q15) * CIN + g * 8;
    const _Float16* Bp = xbT + ((size_t)(b * L + lt * 16 + q15)) * CIN + g * 8;
    f32x4 acc = {0.f, 0.f, 0.f, 0.f};
    #pragma unroll
    for (int c0 = 0; c0 < CIN; c0 += 32) {
        half8 a  = *(const half8*)(Ap + c0);
        half8 bb = *(const half8*)(Bp + c0);
        acc = __builtin_amdgcn_mfma_f32_16x16x32_f16(a, bb, acc, 0, 0, 0);
    }
    int obase = ot * 16 + 4 * g;              // C rows: o = obase + r ; col: l
    int l = lt * 16 + q15;
    if (obase < 256) {                         // Q: scale by DKH^-0.5
        int h = obase >> 5, d0 = obase & 31;
        half4 w;
        #pragma unroll
        for (int r = 0; r < 4; ++r) w[r] = (_Float16)((acc[r] + bqkv[obase + r]) * 0.17677669529663689f);
        *(half4*)(qb + ((size_t)((b * NH + h) * L + l)) * DH + d0) = w;
    } else if (obase < 512) {                  // K
        int o = obase - 256; int h = o >> 5, d0 = o & 31;
        half4 w;
        #pragma unroll
        for (int r = 0; r < 4; ++r) w[r] = (_Float16)(acc[r] + bqkv[obase + r]);
        *(half4*)(kb + ((size_t)((b * NH + h) * L + l)) * DH + d0) = w;
    } else {                                   // V transposed: vt[bh][dv][m]
        int o = obase - 512; int h = o >> 5, d0 = o & 31;
        #pragma unroll
        for (int r = 0; r < 4; ++r)
            vt[((size_t)((b * NH + h) * DH + d0 + r)) * L + l] = (_Float16)(acc[r] + bqkv[obase + r]);
    }
}

// ---------------- kernel 2: relative-logit tables RH[l][rm], RW[l][cm] ----------------
__global__ __launch_bounds__(256) void k_rel(const _Float16* __restrict__ qb, const float* __restrict__ krh,
                                             const float* __restrict__ krw,
                                             float* __restrict__ RH, float* __restrict__ RW) {
    int tid = blockIdx.x * 256 + threadIdx.x; // 1M threads: (bh*L + l) * 32 + j
    int j = tid & 31;
    int t = tid >> 5;                         // (b*NH+h)*L + l
    int l = t & (L - 1);
    int rl = l >> 5, cl = l & 31;
    const _Float16* qp = qb + (size_t)t * DH;
    const float* ph = krh + (j - rl + 31) * DH;
    const float* pw = krw + (j - cl + 31) * DH;
    float sh = 0.f, sw = 0.f;
    #pragma unroll
    for (int d0 = 0; d0 < DH; d0 += 8) {
        half8 v = *(const half8*)(qp + d0);
        #pragma unroll
        for (int jj = 0; jj < 8; ++jj) {
            float qv = (float)v[jj];
            sh += qv * ph[d0 + jj];
            sw += qv * pw[d0 + jj];
        }
    }
    RH[(size_t)t * 32 + j] = sh;
    RW[(size_t)t * 32 + j] = sw;
}

// ---------------- kernel 3: flash attention, m-range split across the block's 4 waves ----------------
__global__ __launch_bounds__(256) void k_attn(const _Float16* __restrict__ qb, const _Float16* __restrict__ kb,
                                              const _Float16* __restrict__ vt, const float* __restrict__ RH,
                                              const float* __restrict__ RW, _Float16* __restrict__ attnT) {
    __shared__ _Float16 Pl[4][16][40];        // per-wave P^T buffer [q][m(32)+pad]
    __shared__ float Cmb[4][64][13];          // per-wave partial {m, l, o[8]}, pad 13 -> conflict-free
    int lane = threadIdx.x & 63, wv = threadIdx.x >> 6;
    int wid = blockIdx.x;                     // 2048 blocks: bh * 64 q-tiles
    int bh = wid >> 6;
    int qbase = (wid & 63) << 4;
    int g = lane >> 4, q15 = lane & 15;
    int l = qbase + q15;

    half8 bq = *(const half8*)(qb + ((size_t)(bh * L + l)) * DH + g * 8);  // B-frag of Q^T

    const float* RWp = RW + ((size_t)(bh * L + l)) * 32;
    float rw0[4], rw1[4];
    #pragma unroll
    for (int r = 0; r < 4; ++r) { rw0[r] = RWp[4 * g + r]; rw1[r] = RWp[16 + 4 * g + r]; }
    const float* RHp = RH + ((size_t)(bh * L + l)) * 32;

    const _Float16* kbase = kb + (size_t)bh * L * DH;
    const _Float16* vbase = vt + (size_t)bh * DH * L;

    float m_run = -1e30f, l_run = 0.f;
    f32x4 o0 = {0.f, 0.f, 0.f, 0.f}, o1 = {0.f, 0.f, 0.f, 0.f};
    const f32x4 zf = {0.f, 0.f, 0.f, 0.f};
    _Float16* plw = &Pl[wv][q15][0];
    const _Float16* plr = &Pl[wv][q15][g * 8];

    for (int ch = wv * 8; ch < wv * 8 + 8; ++ch) {   // each wave owns 8 of the 32 m-chunks
        int m0 = ch * 32;
        half8 k0 = *(const half8*)(kbase + (size_t)(m0 + q15) * DH + g * 8);
        half8 k1 = *(const half8*)(kbase + (size_t)(m0 + 16 + q15) * DH + g * 8);
        f32x4 s0 = __builtin_amdgcn_mfma_f32_16x16x32_f16(k0, bq, zf, 0, 0, 0);  // S^T rows m0+4g+r
        f32x4 s1 = __builtin_amdgcn_mfma_f32_16x16x32_f16(k1, bq, zf, 0, 0, 0);  // rows m0+16+4g+r
        float rh = RHp[ch];                    // row(m) = ch for whole chunk
        float sv[8];
        #pragma unroll
        for (int r = 0; r < 4; ++r) { sv[r] = s0[r] + rh + rw0[r]; sv[4 + r] = s1[r] + rh + rw1[r]; }
        float tmax = sv[0];
        #pragma unroll
        for (int i = 1; i < 8; ++i) tmax = fmaxf(tmax, sv[i]);
        tmax = fmaxf(tmax, __shfl_xor(tmax, 16, 64));
        tmax = fmaxf(tmax, __shfl_xor(tmax, 32, 64));
        float mn = fmaxf(m_run, tmax);
        float scale = __expf(m_run - mn);      // first iter: exp(-huge) -> 0
        float ps = 0.f;
        _Float16 pv[8];
        #pragma unroll
        for (int i = 0; i < 8; ++i) { float p = __expf(sv[i] - mn); ps += p; pv[i] = (_Float16)p; }
        ps += __shfl_xor(ps, 16, 64);
        ps += __shfl_xor(ps, 32, 64);
        l_run = l_run * scale + ps;
        m_run = mn;
        #pragma unroll
        for (int r = 0; r < 4; ++r) { o0[r] *= scale; o1[r] *= scale; }
        half4 w0, w1;
        #pragma unroll
        for (int r = 0; r < 4; ++r) { w0[r] = pv[r]; w1[r] = pv[4 + r]; }
        *(half4*)(plw + 4 * g) = w0;           // m_local 4g..4g+3
        *(half4*)(plw + 16 + 4 * g) = w1;      // m_local 16+4g..+3
        half8 pf = *(const half8*)plr;         // B-frag of P^T: 8 contiguous m for this q
        half8 v0 = *(const half8*)(vbase + (size_t)q15 * L + m0 + g * 8);        // dv 0..15
        half8 v1 = *(const half8*)(vbase + (size_t)(16 + q15) * L + m0 + g * 8); // dv 16..31
        o0 = __builtin_amdgcn_mfma_f32_16x16x32_f16(v0, pf, o0, 0, 0, 0);
        o1 = __builtin_amdgcn_mfma_f32_16x16x32_f16(v1, pf, o1, 0, 0, 0);
    }

    // ---- write per-wave partial (m, l, O[8]) to LDS and combine across the 4 waves ----
    float* cb = &Cmb[wv][lane][0];
    cb[0] = m_run; cb[1] = l_run;
    #pragma unroll
    for (int r = 0; r < 4; ++r) { cb[2 + r] = o0[r]; cb[6 + r] = o1[r]; }
    __syncthreads();
    if (wv == 0) {
        float m0p = Cmb[0][lane][0], m1p = Cmb[1][lane][0];
        float m2p = Cmb[2][lane][0], m3p = Cmb[3][lane][0];
        float ms = fmaxf(fmaxf(m0p, m1p), fmaxf(m2p, m3p));
        float lsum = 0.f;
        float O[8];
        #pragma unroll
        for (int j = 0; j < 8; ++j) O[j] = 0.f;
        #pragma unroll
        for (int i = 0; i < 4; ++i) {
            float sc = __expf(Cmb[i][lane][0] - ms);
            lsum += sc * Cmb[i][lane][1];
            #pragma unroll
            for (int j = 0; j < 8; ++j) O[j] += sc * Cmb[i][lane][2 + j];
        }
        float inv = 1.f / lsum;
        int b = bh >> 3, h = bh & 7;
        _Float16* op = attnT + ((size_t)(b * L + l)) * CIN + h * DH;
        half4 e0, e1;
        #pragma unroll
        for (int r = 0; r < 4; ++r) { e0[r] = (_Float16)(O[r] * inv); e1[r] = (_Float16)(O[4 + r] * inv); }
        *(half4*)(op + 4 * g) = e0;            // dv = 4g+r
        *(half4*)(op + 16 + 4 * g) = e1;       // dv = 16+4g+r
    }
}

// ---------------- kernel 4: output projections + concat ----------------
__global__ __launch_bounds__(256) void k_out(const _Float16* __restrict__ xbT, const _Float16* __restrict__ attnT,
                                             const _Float16* __restrict__ wob, const _Float16* __restrict__ wab,
                                             const float* __restrict__ bout, const float* __restrict__ battn,
                                             float* __restrict__ out) {
    int lane = threadIdx.x & 63, wv = threadIdx.x >> 6;
    int wid = blockIdx.x * 4 + wv;             // 8192 waves: b * (32 ch-tiles) * (64 l-tiles)
    int b = wid >> 11; int rem = wid & 2047;
    int ct = rem >> 6, lt = rem & 63;
    int g = lane >> 4, q15 = lane & 15;
    int ch0 = ct * 16;
    int l = lt * 16 + q15;
    bool is_conv = ch0 < 256;
    const _Float16* Ap = (is_conv ? wob + ch0 * CIN : wab + (ch0 - 256) * CIN) + q15 * CIN + g * 8;
    const _Float16* Bp = (is_conv ? xbT : attnT) + ((size_t)(b * L + l)) * CIN + g * 8;
    f32x4 acc = {0.f, 0.f, 0.f, 0.f};
    #pragma unroll
    for (int c0 = 0; c0 < CIN; c0 += 32) {
        acc = __builtin_amdgcn_mfma_f32_16x16x32_f16(*(const half8*)(Ap + c0), *(const half8*)(Bp + c0),
                                                     acc, 0, 0, 0);
    }
    #pragma unroll
    for (int r = 0; r < 4; ++r) {
        int chv = ch0 + 4 * g + r;
        float bv = is_conv ? bout[chv] : battn[chv - 256];
        out[((size_t)(b * COUT + chv)) * L + l] = acc[r] + bv;
    }
}

extern "C" void kernel_launch(void* const* d_in, const int* in_sizes, int n_in,
                              void* d_out, int out_size, void* d_ws, size_t ws_size,
                              hipStream_t stream) {
    const float* x      = (const float*)d_in[0];
    const float* w_qkv  = (const float*)d_in[1];
    const float* b_qkv  = (const float*)d_in[2];
    const float* w_attn = (const float*)d_in[3];
    const float* b_attn = (const float*)d_in[4];
    const float* w_out  = (const float*)d_in[5];
    const float* b_out  = (const float*)d_in[6];
    const float* krh    = (const float*)d_in[7];
    const float* krw    = (const float*)d_in[8];

    char* ws = (char*)d_ws;
    _Float16* xbT = (_Float16*)(ws);                    // 2 MB
    _Float16* wqb = (_Float16*)(ws + 2097152);          // 384 KB
    _Float16* wab = (_Float16*)(ws + 2490368);          // 128 KB
    _Float16* wob = (_Float16*)(ws + 2621440);          // 128 KB
    _Float16* qb  = (_Float16*)(ws + 2752512);          // 2 MB
    _Float16* kb  = (_Float16*)(ws + 4849664);          // 2 MB
    _Float16* vt  = (_Float16*)(ws + 6946816);          // 2 MB
    float*    RH  = (float*)   (ws + 9043968);          // 4 MB
    float*    RW  = (float*)   (ws + 13238272);         // 4 MB
    _Float16* attnT = (_Float16*)(ws + 17432576);       // 2 MB
    float* out = (float*)d_out;

    k_prep<<<dim3(784),  dim3(256), 0, stream>>>(x, w_qkv, w_attn, w_out, xbT, wqb, wab, wob);
    k_qkv <<<dim3(3072), dim3(256), 0, stream>>>(xbT, wqb, b_qkv, qb, kb, vt);
    k_rel <<<dim3(4096), dim3(256), 0, stream>>>(qb, krh, krw, RH, RW);
    k_attn<<<dim3(2048), dim3(256), 0, stream>>>(qb, kb, vt, RH, RW, attnT);
    k_out <<<dim3(2048), dim3(256), 0, stream>>>(xbT, attnT, wob, wab, b_out, b_attn, out);
}

// Round 3
// 94.040 us; speedup vs baseline: 1.3498x; 1.3498x over previous
//
#include <hip/hip_runtime.h>

#define NB   4
#define CIN  256
#define L    1024
#define NH   8
#define DH   32
#define COUT 512

typedef _Float16 half8 __attribute__((ext_vector_type(8)));
typedef _Float16 half4 __attribute__((ext_vector_type(4)));
typedef float    f32x4 __attribute__((ext_vector_type(4)));

// ---------------- kernel 0: prep — x (B,C,H,W) -> xT (B,L,C) f16 ; weights -> f16 ; Wrel ----------------
__global__ __launch_bounds__(256) void k_prep(const float* __restrict__ x, const float* __restrict__ wq,
                                              const float* __restrict__ wa, const float* __restrict__ wo,
                                              const float* __restrict__ krh, const float* __restrict__ krw,
                                              _Float16* __restrict__ xbT, _Float16* __restrict__ wqb,
                                              _Float16* __restrict__ wab, _Float16* __restrict__ wob,
                                              _Float16* __restrict__ wrel) {
    int blk = blockIdx.x;
    if (blk < 128) {
        // x transpose: 32768 threads, thread = (b,l, c-eighth); 32 channels each
        int idx = blk * 256 + threadIdx.x;
        int eighth = idx & 7;
        int bl = idx >> 3;                     // b*L + l
        int b = bl >> 10, l = bl & (L - 1);
        int c0 = eighth * 32;
        const float* xp = x + (size_t)b * CIN * L + l;
        _Float16* op = xbT + (size_t)bl * CIN + c0;
        #pragma unroll
        for (int v = 0; v < 4; ++v) {
            half8 w;
            #pragma unroll
            for (int j = 0; j < 8; ++j) w[j] = (_Float16)xp[(c0 + v * 8 + j) * L];
            *(half8*)(op + v * 8) = w;
        }
    } else {
        int i = (blk - 128) * 256 + threadIdx.x;
        if (i < 768 * 256) wqb[i] = (_Float16)wq[i];
        if (i < 256 * 256) { wab[i] = (_Float16)wa[i]; wob[i] = (_Float16)wo[i]; }
        if (i < 4096) {
            // Wrel f16 [128][32]: rows 0..62 = krh, 63 = 0, 64..126 = krw, 127 = 0
            int half_sel = i >> 11;            // 0: h, 1: w
            int j = i & 2047;
            float v = 0.f;
            if (j < 63 * 32) v = half_sel ? krw[j] : krh[j];
            wrel[i] = (_Float16)v;
        }
    }
}

// ---------------- kernel 1: QKV projection (MFMA), writes q(scaled)/k rows + v transposed ----------------
__global__ __launch_bounds__(256) void k_qkv(const _Float16* __restrict__ xbT, const _Float16* __restrict__ wqb,
                                             const float* __restrict__ bqkv,
                                             _Float16* __restrict__ qb, _Float16* __restrict__ kb,
                                             _Float16* __restrict__ vt) {
    int lane = threadIdx.x & 63, wv = threadIdx.x >> 6;
    int wid = blockIdx.x * 4 + wv;            // 12288 waves: b * (48 o-tiles) * (64 l-tiles)
    int b = wid / 3072; int rem = wid - b * 3072;
    int ot = rem >> 6, lt = rem & 63;
    int g = lane >> 4, q15 = lane & 15;
    const _Float16* Ap = wqb + (ot * 16 + q15) * CIN + g * 8;
    const _Float16* Bp = xbT + ((size_t)(b * L + lt * 16 + q15)) * CIN + g * 8;
    f32x4 acc = {0.f, 0.f, 0.f, 0.f};
    #pragma unroll
    for (int c0 = 0; c0 < CIN; c0 += 32) {
        half8 a  = *(const half8*)(Ap + c0);
        half8 bb = *(const half8*)(Bp + c0);
        acc = __builtin_amdgcn_mfma_f32_16x16x32_f16(a, bb, acc, 0, 0, 0);
    }
    int obase = ot * 16 + 4 * g;              // C rows: o = obase + r ; col: l
    int l = lt * 16 + q15;
    if (obase < 256) {                         // Q: scale by DKH^-0.5
        int h = obase >> 5, d0 = obase & 31;
        half4 w;
        #pragma unroll
        for (int r = 0; r < 4; ++r) w[r] = (_Float16)((acc[r] + bqkv[obase + r]) * 0.17677669529663689f);
        *(half4*)(qb + ((size_t)((b * NH + h) * L + l)) * DH + d0) = w;
    } else if (obase < 512) {                  // K
        int o = obase - 256; int h = o >> 5, d0 = o & 31;
        half4 w;
        #pragma unroll
        for (int r = 0; r < 4; ++r) w[r] = (_Float16)(acc[r] + bqkv[obase + r]);
        *(half4*)(kb + ((size_t)((b * NH + h) * L + l)) * DH + d0) = w;
    } else {                                   // V transposed: vt[bh][dv][m]
        int o = obase - 512; int h = o >> 5, d0 = o & 31;
        #pragma unroll
        for (int r = 0; r < 4; ++r)
            vt[((size_t)((b * NH + h) * DH + d0 + r)) * L + l] = (_Float16)(acc[r] + bqkv[obase + r]);
    }
}

// ---------------- kernel 2: rel-logit table RT[bh][l][128] = q . [krh | krw]^T via MFMA ----------------
__global__ __launch_bounds__(256) void k_rel2(const _Float16* __restrict__ qb, const _Float16* __restrict__ wrel,
                                              float* __restrict__ RT) {
    int lane = threadIdx.x & 63, wv = threadIdx.x >> 6;
    int wid = blockIdx.x * 4 + wv;            // 16384 waves: bh * (64 lt) * (8 ot)
    int bh = wid >> 9;
    int rem = wid & 511;
    int lt = rem >> 3, ot = rem & 7;
    int g = lane >> 4, q15 = lane & 15;
    int l = lt * 16 + q15;
    half8 a = *(const half8*)(wrel + (ot * 16 + q15) * DH + g * 8);
    half8 b = *(const half8*)(qb + ((size_t)(bh * L + l)) * DH + g * 8);
    f32x4 acc = {0.f, 0.f, 0.f, 0.f};
    acc = __builtin_amdgcn_mfma_f32_16x16x32_f16(a, b, acc, 0, 0, 0);
    // C: row = ot*16+4g+r (rel-row), col = l
    *(f32x4*)(RT + ((size_t)(bh * L + l)) * 128 + ot * 16 + 4 * g) = acc;
}

// ---------------- kernel 3: flash attention, m-range split across the block's 4 waves ----------------
__global__ __launch_bounds__(256) void k_attn(const _Float16* __restrict__ qb, const _Float16* __restrict__ kb,
                                              const _Float16* __restrict__ vt, const float* __restrict__ RT,
                                              _Float16* __restrict__ attnT) {
    __shared__ _Float16 Pl[4][16][40];        // per-wave P^T buffer [q][m(32)+pad]
    __shared__ float Cmb[4][64][13];          // per-wave partial {m, l, o[8]}, pad 13 -> conflict-free
    int lane = threadIdx.x & 63, wv = threadIdx.x >> 6;
    int wid = blockIdx.x;                     // 2048 blocks: bh * 64 q-tiles
    int bh = wid >> 6;
    int qbase = (wid & 63) << 4;
    int g = lane >> 4, q15 = lane & 15;
    int l = qbase + q15;
    int rl = l >> 5, cl = l & 31;

    half8 bq = *(const half8*)(qb + ((size_t)(bh * L + l)) * DH + g * 8);  // B-frag of Q^T

    const float* RTp = RT + ((size_t)(bh * L + l)) * 128;
    float rw0[4], rw1[4];
    #pragma unroll
    for (int r = 0; r < 4; ++r) {
        rw0[r] = RTp[95 + 4 * g + r - cl];     // 64 + (4g+r) - cl + 31
        rw1[r] = RTp[111 + 4 * g + r - cl];    // 64 + (16+4g+r) - cl + 31
    }

    const _Float16* kbase = kb + (size_t)bh * L * DH;
    const _Float16* vbase = vt + (size_t)bh * DH * L;

    float m_run = -1e30f, l_run = 0.f;
    f32x4 o0 = {0.f, 0.f, 0.f, 0.f}, o1 = {0.f, 0.f, 0.f, 0.f};
    const f32x4 zf = {0.f, 0.f, 0.f, 0.f};
    _Float16* plw = &Pl[wv][q15][0];
    const _Float16* plr = &Pl[wv][q15][g * 8];

    for (int ch = wv * 8; ch < wv * 8 + 8; ++ch) {   // each wave owns 8 of the 32 m-chunks
        int m0 = ch * 32;
        half8 k0 = *(const half8*)(kbase + (size_t)(m0 + q15) * DH + g * 8);
        half8 k1 = *(const half8*)(kbase + (size_t)(m0 + 16 + q15) * DH + g * 8);
        f32x4 s0 = __builtin_amdgcn_mfma_f32_16x16x32_f16(k0, bq, zf, 0, 0, 0);  // S^T rows m0+4g+r
        f32x4 s1 = __builtin_amdgcn_mfma_f32_16x16x32_f16(k1, bq, zf, 0, 0, 0);  // rows m0+16+4g+r
        float rh = RTp[ch - rl + 31];          // row(m) = ch for whole chunk
        float sv[8];
        #pragma unroll
        for (int r = 0; r < 4; ++r) { sv[r] = s0[r] + rh + rw0[r]; sv[4 + r] = s1[r] + rh + rw1[r]; }
        float tmax = sv[0];
        #pragma unroll
        for (int i = 1; i < 8; ++i) tmax = fmaxf(tmax, sv[i]);
        tmax = fmaxf(tmax, __shfl_xor(tmax, 16, 64));
        tmax = fmaxf(tmax, __shfl_xor(tmax, 32, 64));
        float mn = fmaxf(m_run, tmax);
        float scale = __expf(m_run - mn);      // first iter: exp(-huge) -> 0
        float ps = 0.f;
        _Float16 pv[8];
        #pragma unroll
        for (int i = 0; i < 8; ++i) { float p = __expf(sv[i] - mn); ps += p; pv[i] = (_Float16)p; }
        ps += __shfl_xor(ps, 16, 64);
        ps += __shfl_xor(ps, 32, 64);
        l_run = l_run * scale + ps;
        m_run = mn;
        #pragma unroll
        for (int r = 0; r < 4; ++r) { o0[r] *= scale; o1[r] *= scale; }
        half4 w0, w1;
        #pragma unroll
        for (int r = 0; r < 4; ++r) { w0[r] = pv[r]; w1[r] = pv[4 + r]; }
        *(half4*)(plw + 4 * g) = w0;           // m_local 4g..4g+3
        *(half4*)(plw + 16 + 4 * g) = w1;      // m_local 16+4g..+3
        half8 pf = *(const half8*)plr;         // B-frag of P^T: 8 contiguous m for this q
        half8 v0 = *(const half8*)(vbase + (size_t)q15 * L + m0 + g * 8);        // dv 0..15
        half8 v1 = *(const half8*)(vbase + (size_t)(16 + q15) * L + m0 + g * 8); // dv 16..31
        o0 = __builtin_amdgcn_mfma_f32_16x16x32_f16(v0, pf, o0, 0, 0, 0);
        o1 = __builtin_amdgcn_mfma_f32_16x16x32_f16(v1, pf, o1, 0, 0, 0);
    }

    // ---- write per-wave partial (m, l, O[8]) to LDS and combine across the 4 waves ----
    float* cb = &Cmb[wv][lane][0];
    cb[0] = m_run; cb[1] = l_run;
    #pragma unroll
    for (int r = 0; r < 4; ++r) { cb[2 + r] = o0[r]; cb[6 + r] = o1[r]; }
    __syncthreads();
    if (wv == 0) {
        float m0p = Cmb[0][lane][0], m1p = Cmb[1][lane][0];
        float m2p = Cmb[2][lane][0], m3p = Cmb[3][lane][0];
        float ms = fmaxf(fmaxf(m0p, m1p), fmaxf(m2p, m3p));
        float lsum = 0.f;
        float O[8];
        #pragma unroll
        for (int j = 0; j < 8; ++j) O[j] = 0.f;
        #pragma unroll
        for (int i = 0; i < 4; ++i) {
            float sc = __expf(Cmb[i][lane][0] - ms);
            lsum += sc * Cmb[i][lane][1];
            #pragma unroll
            for (int j = 0; j < 8; ++j) O[j] += sc * Cmb[i][lane][2 + j];
        }
        float inv = 1.f / lsum;
        int b = bh >> 3, h = bh & 7;
        _Float16* op = attnT + ((size_t)(b * L + l)) * CIN + h * DH;
        half4 e0, e1;
        #pragma unroll
        for (int r = 0; r < 4; ++r) { e0[r] = (_Float16)(O[r] * inv); e1[r] = (_Float16)(O[4 + r] * inv); }
        *(half4*)(op + 4 * g) = e0;            // dv = 4g+r
        *(half4*)(op + 16 + 4 * g) = e1;       // dv = 16+4g+r
    }
}

// ---------------- kernel 4: output projections + concat ----------------
__global__ __launch_bounds__(256) void k_out(const _Float16* __restrict__ xbT, const _Float16* __restrict__ attnT,
                                             const _Float16* __restrict__ wob, const _Float16* __restrict__ wab,
                                             const float* __restrict__ bout, const float* __restrict__ battn,
                                             float* __restrict__ out) {
    int lane = threadIdx.x & 63, wv = threadIdx.x >> 6;
    int wid = blockIdx.x * 4 + wv;             // 8192 waves: b * (32 ch-tiles) * (64 l-tiles)
    int b = wid >> 11; int rem = wid & 2047;
    int ct = rem >> 6, lt = rem & 63;
    int g = lane >> 4, q15 = lane & 15;
    int ch0 = ct * 16;
    int l = lt * 16 + q15;
    bool is_conv = ch0 < 256;
    const _Float16* Ap = (is_conv ? wob + ch0 * CIN : wab + (ch0 - 256) * CIN) + q15 * CIN + g * 8;
    const _Float16* Bp = (is_conv ? xbT : attnT) + ((size_t)(b * L + l)) * CIN + g * 8;
    f32x4 acc = {0.f, 0.f, 0.f, 0.f};
    #pragma unroll
    for (int c0 = 0; c0 < CIN; c0 += 32) {
        acc = __builtin_amdgcn_mfma_f32_16x16x32_f16(*(const half8*)(Ap + c0), *(const half8*)(Bp + c0),
                                                     acc, 0, 0, 0);
    }
    #pragma unroll
    for (int r = 0; r < 4; ++r) {
        int chv = ch0 + 4 * g + r;
        float bv = is_conv ? bout[chv] : battn[chv - 256];
        out[((size_t)(b * COUT + chv)) * L + l] = acc[r] + bv;
    }
}

extern "C" void kernel_launch(void* const* d_in, const int* in_sizes, int n_in,
                              void* d_out, int out_size, void* d_ws, size_t ws_size,
                              hipStream_t stream) {
    const float* x      = (const float*)d_in[0];
    const float* w_qkv  = (const float*)d_in[1];
    const float* b_qkv  = (const float*)d_in[2];
    const float* w_attn = (const float*)d_in[3];
    const float* b_attn = (const float*)d_in[4];
    const float* w_out  = (const float*)d_in[5];
    const float* b_out  = (const float*)d_in[6];
    const float* krh    = (const float*)d_in[7];
    const float* krw    = (const float*)d_in[8];

    char* ws = (char*)d_ws;
    _Float16* xbT  = (_Float16*)(ws);                   // 2 MB
    _Float16* wqb  = (_Float16*)(ws + 2097152);         // 384 KB
    _Float16* wab  = (_Float16*)(ws + 2490368);         // 128 KB
    _Float16* wob  = (_Float16*)(ws + 2621440);         // 128 KB
    _Float16* wrel = (_Float16*)(ws + 2752512);         // 8 KB  (128x32 f16)
    _Float16* qb   = (_Float16*)(ws + 2760704);         // 2 MB
    _Float16* kb   = (_Float16*)(ws + 4857856);         // 2 MB
    _Float16* vt   = (_Float16*)(ws + 6955008);         // 2 MB
    float*    RT   = (float*)   (ws + 9052160);         // 16 MB (32x1024x128 f32)
    _Float16* attnT= (_Float16*)(ws + 25829376);        // 2 MB
    float* out = (float*)d_out;

    k_prep<<<dim3(896),  dim3(256), 0, stream>>>(x, w_qkv, w_attn, w_out, krh, krw,
                                                 xbT, wqb, wab, wob, wrel);
    k_qkv <<<dim3(3072), dim3(256), 0, stream>>>(xbT, wqb, b_qkv, qb, kb, vt);
    k_rel2<<<dim3(4096), dim3(256), 0, stream>>>(qb, wrel, RT);
    k_attn<<<dim3(2048), dim3(256), 0, stream>>>(qb, kb, vt, RT, attnT);
    k_out <<<dim3(2048), dim3(256), 0, stream>>>(xbT, attnT, wob, wab, b_out, b_attn, out);
}

// Round 4
// 61.826 us; speedup vs baseline: 2.0531x; 1.5210x over previous
//
#include <hip/hip_runtime.h>

#define NB   4
#define CIN  256
#define L    1024
#define NH   8
#define DH   32
#define COUT 512

typedef _Float16 half8 __attribute__((ext_vector_type(8)));
typedef _Float16 half4 __attribute__((ext_vector_type(4)));
typedef float    f32x4 __attribute__((ext_vector_type(4)));

// ---------------- kernel 0: prep — x (B,C,H,W) -> xT (B,L,C) f16 ; weights -> f16 ; Wrel ----------------
__global__ __launch_bounds__(256) void k_prep(const float* __restrict__ x, const float* __restrict__ wq,
                                              const float* __restrict__ wa, const float* __restrict__ wo,
                                              const float* __restrict__ krh, const float* __restrict__ krw,
                                              _Float16* __restrict__ xbT, _Float16* __restrict__ wqb,
                                              _Float16* __restrict__ wab, _Float16* __restrict__ wob,
                                              _Float16* __restrict__ wrel) {
    int blk = blockIdx.x;
    if (blk < 128) {
        // x transpose: 32768 threads, thread = (b,l, c-eighth); 32 channels each
        int idx = blk * 256 + threadIdx.x;
        int eighth = idx & 7;
        int bl = idx >> 3;                     // b*L + l
        int b = bl >> 10, l = bl & (L - 1);
        int c0 = eighth * 32;
        const float* xp = x + (size_t)b * CIN * L + l;
        _Float16* op = xbT + (size_t)bl * CIN + c0;
        #pragma unroll
        for (int v = 0; v < 4; ++v) {
            half8 w;
            #pragma unroll
            for (int j = 0; j < 8; ++j) w[j] = (_Float16)xp[(c0 + v * 8 + j) * L];
            *(half8*)(op + v * 8) = w;
        }
    } else {
        int i = (blk - 128) * 256 + threadIdx.x;
        if (i < 768 * 256) wqb[i] = (_Float16)wq[i];
        if (i < 256 * 256) { wab[i] = (_Float16)wa[i]; wob[i] = (_Float16)wo[i]; }
        if (i < 4096) {
            // Wrel f16 [128][32]: rows 0..62 = krh, 63 = 0, 64..126 = krw, 127 = 0
            int half_sel = i >> 11;            // 0: h, 1: w
            int j = i & 2047;
            float v = 0.f;
            if (j < 63 * 32) v = half_sel ? krw[j] : krh[j];
            wrel[i] = (_Float16)v;
        }
    }
}

// ---------------- kernel 1: QKV projection, 32x32 tile/wave (4 MFMA per 4 loads) ----------------
__global__ __launch_bounds__(256) void k_qkv(const _Float16* __restrict__ xbT, const _Float16* __restrict__ wqb,
                                             const float* __restrict__ bqkv,
                                             _Float16* __restrict__ qb, _Float16* __restrict__ kb,
                                             _Float16* __restrict__ vt) {
    int lane = threadIdx.x & 63, wv = threadIdx.x >> 6;
    int wid = blockIdx.x * 4 + wv;            // 3072 waves: b * (24 ot) * (32 lt)
    int b = wid / 768; int rem = wid - b * 768;
    int ot = rem >> 5, lt = rem & 31;
    int g = lane >> 4, q15 = lane & 15;
    int o0 = ot * 32, l0 = lt * 32;
    const _Float16* A0 = wqb + (size_t)(o0 + q15) * CIN + g * 8;
    const _Float16* B0 = xbT + ((size_t)(b * L + l0 + q15)) * CIN + g * 8;
    f32x4 acc00 = {0,0,0,0}, acc01 = {0,0,0,0}, acc10 = {0,0,0,0}, acc11 = {0,0,0,0};
    #pragma unroll
    for (int c0 = 0; c0 < CIN; c0 += 32) {
        half8 a0 = *(const half8*)(A0 + c0);
        half8 a1 = *(const half8*)(A0 + 16 * CIN + c0);
        half8 b0 = *(const half8*)(B0 + c0);
        half8 b1 = *(const half8*)(B0 + 16 * CIN + c0);
        acc00 = __builtin_amdgcn_mfma_f32_16x16x32_f16(a0, b0, acc00, 0, 0, 0);
        acc01 = __builtin_amdgcn_mfma_f32_16x16x32_f16(a0, b1, acc01, 0, 0, 0);
        acc10 = __builtin_amdgcn_mfma_f32_16x16x32_f16(a1, b0, acc10, 0, 0, 0);
        acc11 = __builtin_amdgcn_mfma_f32_16x16x32_f16(a1, b1, acc11, 0, 0, 0);
    }
    #pragma unroll
    for (int ai = 0; ai < 2; ++ai) {
        int obase = o0 + ai * 16 + 4 * g;
        float bs0 = bqkv[obase], bs1 = bqkv[obase + 1], bs2 = bqkv[obase + 2], bs3 = bqkv[obase + 3];
        #pragma unroll
        for (int bj = 0; bj < 2; ++bj) {
            f32x4 a = (ai == 0) ? (bj == 0 ? acc00 : acc01) : (bj == 0 ? acc10 : acc11);
            float av[4] = {a[0] + bs0, a[1] + bs1, a[2] + bs2, a[3] + bs3};
            int l = l0 + bj * 16 + q15;
            if (obase < 256) {                 // Q: scale by DKH^-0.5
                int h = obase >> 5, d0 = obase & 31;
                half4 w;
                #pragma unroll
                for (int r = 0; r < 4; ++r) w[r] = (_Float16)(av[r] * 0.17677669529663689f);
                *(half4*)(qb + ((size_t)((b * NH + h) * L + l)) * DH + d0) = w;
            } else if (obase < 512) {          // K
                int o = obase - 256; int h = o >> 5, d0 = o & 31;
                half4 w;
                #pragma unroll
                for (int r = 0; r < 4; ++r) w[r] = (_Float16)av[r];
                *(half4*)(kb + ((size_t)((b * NH + h) * L + l)) * DH + d0) = w;
            } else {                           // V transposed: vt[bh][dv][m]
                int o = obase - 512; int h = o >> 5, d0 = o & 31;
                #pragma unroll
                for (int r = 0; r < 4; ++r)
                    vt[((size_t)((b * NH + h) * DH + d0 + r)) * L + l] = (_Float16)av[r];
            }
        }
    }
}

// ---------------- kernel 2: flash attention; rel table computed in-block; split-m across 4 waves ----------------
__global__ __launch_bounds__(256) void k_attn(const _Float16* __restrict__ qb, const _Float16* __restrict__ kb,
                                              const _Float16* __restrict__ vt, const _Float16* __restrict__ wrel,
                                              _Float16* __restrict__ attnT) {
    __shared__ float SM[4][640];              // per-wave: P^T halfs (320 f) aliased with combine (640 f)
    __shared__ float RelS[128 * 16];          // rel table [rel-row][q]
    int lane = threadIdx.x & 63, wv = threadIdx.x >> 6;
    int wid = blockIdx.x;                     // 2048 blocks: bh * 64 q-tiles
    int bh = wid >> 6;
    int qbase = (wid & 63) << 4;
    int g = lane >> 4, q15 = lane & 15;
    int l = qbase + q15;
    int rl = qbase >> 5;                      // same for all q in tile
    int cl = (qbase & 31) + q15;

    half8 bq = *(const half8*)(qb + ((size_t)(bh * L + l)) * DH + g * 8);  // B-frag of Q^T
    const f32x4 zf = {0.f, 0.f, 0.f, 0.f};

    // ---- rel table: RelS[rr][q15] = q_l . wrel[rr], rr in [0,128) ; wave wv does rows [32wv,32wv+32) ----
    #pragma unroll
    for (int s = 0; s < 2; ++s) {
        int rr0 = 32 * wv + 16 * s;
        half8 wa = *(const half8*)(wrel + (rr0 + q15) * DH + g * 8);
        f32x4 rc = __builtin_amdgcn_mfma_f32_16x16x32_f16(wa, bq, zf, 0, 0, 0);
        #pragma unroll
        for (int r = 0; r < 4; ++r) RelS[(rr0 + 4 * g + r) * 16 + q15] = rc[r];
    }
    __syncthreads();

    float rw0[4], rw1[4];
    #pragma unroll
    for (int r = 0; r < 4; ++r) {
        rw0[r] = RelS[(95 + 4 * g + r - cl) * 16 + q15];   // rel-row 64 + (4g+r) - cl + 31
        rw1[r] = RelS[(111 + 4 * g + r - cl) * 16 + q15];  // rel-row 64 + (16+4g+r) - cl + 31
    }

    const _Float16* kbase = kb + (size_t)bh * L * DH;
    const _Float16* vbase = vt + (size_t)bh * DH * L;

    float m_run = -1e30f, l_run = 0.f;
    f32x4 o0 = {0.f, 0.f, 0.f, 0.f}, o1 = {0.f, 0.f, 0.f, 0.f};
    _Float16* plw = (_Float16*)&SM[wv][0] + q15 * 40;
    const _Float16* plr = (_Float16*)&SM[wv][0] + q15 * 40 + g * 8;

    for (int ch = wv * 8; ch < wv * 8 + 8; ++ch) {   // each wave owns 8 of the 32 m-chunks
        int m0 = ch * 32;
        half8 k0 = *(const half8*)(kbase + (size_t)(m0 + q15) * DH + g * 8);
        half8 k1 = *(const half8*)(kbase + (size_t)(m0 + 16 + q15) * DH + g * 8);
        f32x4 s0 = __builtin_amdgcn_mfma_f32_16x16x32_f16(k0, bq, zf, 0, 0, 0);  // S^T rows m0+4g+r
        f32x4 s1 = __builtin_amdgcn_mfma_f32_16x16x32_f16(k1, bq, zf, 0, 0, 0);  // rows m0+16+4g+r
        float rh = RelS[(ch + 31 - rl) * 16 + q15];  // row(m) = ch for whole chunk
        float sv[8];
        #pragma unroll
        for (int r = 0; r < 4; ++r) { sv[r] = s0[r] + rh + rw0[r]; sv[4 + r] = s1[r] + rh + rw1[r]; }
        float tmax = sv[0];
        #pragma unroll
        for (int i = 1; i < 8; ++i) tmax = fmaxf(tmax, sv[i]);
        tmax = fmaxf(tmax, __shfl_xor(tmax, 16, 64));
        tmax = fmaxf(tmax, __shfl_xor(tmax, 32, 64));
        float mn = fmaxf(m_run, tmax);
        float scale = __expf(m_run - mn);      // first iter: exp(-huge) -> 0
        float ps = 0.f;
        _Float16 pv[8];
        #pragma unroll
        for (int i = 0; i < 8; ++i) { float p = __expf(sv[i] - mn); ps += p; pv[i] = (_Float16)p; }
        ps += __shfl_xor(ps, 16, 64);
        ps += __shfl_xor(ps, 32, 64);
        l_run = l_run * scale + ps;
        m_run = mn;
        #pragma unroll
        for (int r = 0; r < 4; ++r) { o0[r] *= scale; o1[r] *= scale; }
        half4 w0, w1;
        #pragma unroll
        for (int r = 0; r < 4; ++r) { w0[r] = pv[r]; w1[r] = pv[4 + r]; }
        *(half4*)(plw + 4 * g) = w0;           // m_local 4g..4g+3
        *(half4*)(plw + 16 + 4 * g) = w1;      // m_local 16+4g..+3
        half8 pf = *(const half8*)plr;         // B-frag of P^T: 8 contiguous m for this q
        half8 v0 = *(const half8*)(vbase + (size_t)q15 * L + m0 + g * 8);        // dv 0..15
        half8 v1 = *(const half8*)(vbase + (size_t)(16 + q15) * L + m0 + g * 8); // dv 16..31
        o0 = __builtin_amdgcn_mfma_f32_16x16x32_f16(v0, pf, o0, 0, 0, 0);
        o1 = __builtin_amdgcn_mfma_f32_16x16x32_f16(v1, pf, o1, 0, 0, 0);
    }

    // ---- write per-wave partial (m, l, O[8]) into SM (aliases this wave's own P buffer) ----
    float* cw = &SM[wv][lane * 10];
    cw[0] = m_run; cw[1] = l_run;
    #pragma unroll
    for (int r = 0; r < 4; ++r) { cw[2 + r] = o0[r]; cw[6 + r] = o1[r]; }
    __syncthreads();
    if (wv == 0) {
        float ms = -1e30f;
        #pragma unroll
        for (int i = 0; i < 4; ++i) ms = fmaxf(ms, SM[i][lane * 10]);
        float lsum = 0.f;
        float O[8];
        #pragma unroll
        for (int j = 0; j < 8; ++j) O[j] = 0.f;
        #pragma unroll
        for (int i = 0; i < 4; ++i) {
            const float* cr = &SM[i][lane * 10];
            float sc = __expf(cr[0] - ms);
            lsum += sc * cr[1];
            #pragma unroll
            for (int j = 0; j < 8; ++j) O[j] += sc * cr[2 + j];
        }
        float inv = 1.f / lsum;
        int b = bh >> 3, h = bh & 7;
        _Float16* op = attnT + ((size_t)(b * L + l)) * CIN + h * DH;
        half4 e0, e1;
        #pragma unroll
        for (int r = 0; r < 4; ++r) { e0[r] = (_Float16)(O[r] * inv); e1[r] = (_Float16)(O[4 + r] * inv); }
        *(half4*)(op + 4 * g) = e0;            // dv = 4g+r
        *(half4*)(op + 16 + 4 * g) = e1;       // dv = 16+4g+r
    }
}

// ---------------- kernel 3: output projections + concat, 32x32 tile/wave ----------------
__global__ __launch_bounds__(256) void k_out(const _Float16* __restrict__ xbT, const _Float16* __restrict__ attnT,
                                             const _Float16* __restrict__ wob, const _Float16* __restrict__ wab,
                                             const float* __restrict__ bout, const float* __restrict__ battn,
                                             float* __restrict__ out) {
    int lane = threadIdx.x & 63, wv = threadIdx.x >> 6;
    int wid = blockIdx.x * 4 + wv;             // 2048 waves: b * (16 ct) * (32 lt)
    int b = wid >> 9; int rem = wid & 511;
    int ct = rem >> 5, lt = rem & 31;
    int g = lane >> 4, q15 = lane & 15;
    int ch0 = ct * 32, l0 = lt * 32;
    bool is_conv = ch0 < 256;
    const _Float16* A0 = (is_conv ? wob + (size_t)ch0 * CIN : wab + (size_t)(ch0 - 256) * CIN) + q15 * CIN + g * 8;
    const _Float16* B0 = (is_conv ? xbT : attnT) + ((size_t)(b * L + l0 + q15)) * CIN + g * 8;
    f32x4 acc00 = {0,0,0,0}, acc01 = {0,0,0,0}, acc10 = {0,0,0,0}, acc11 = {0,0,0,0};
    #pragma unroll
    for (int c0 = 0; c0 < CIN; c0 += 32) {
        half8 a0 = *(const half8*)(A0 + c0);
        half8 a1 = *(const half8*)(A0 + 16 * CIN + c0);
        half8 b0 = *(const half8*)(B0 + c0);
        half8 b1 = *(const half8*)(B0 + 16 * CIN + c0);
        acc00 = __builtin_amdgcn_mfma_f32_16x16x32_f16(a0, b0, acc00, 0, 0, 0);
        acc01 = __builtin_amdgcn_mfma_f32_16x16x32_f16(a0, b1, acc01, 0, 0, 0);
        acc10 = __builtin_amdgcn_mfma_f32_16x16x32_f16(a1, b0, acc10, 0, 0, 0);
        acc11 = __builtin_amdgcn_mfma_f32_16x16x32_f16(a1, b1, acc11, 0, 0, 0);
    }
    #pragma unroll
    for (int ai = 0; ai < 2; ++ai) {
        int chb = ch0 + ai * 16 + 4 * g;
        float bs[4];
        #pragma unroll
        for (int r = 0; r < 4; ++r) bs[r] = is_conv ? bout[chb + r] : battn[chb + r - 256];
        #pragma unroll
        for (int bj = 0; bj < 2; ++bj) {
            f32x4 a = (ai == 0) ? (bj == 0 ? acc00 : acc01) : (bj == 0 ? acc10 : acc11);
            int l = l0 + bj * 16 + q15;
            #pragma unroll
            for (int r = 0; r < 4; ++r)
                out[((size_t)(b * COUT + chb + r)) * L + l] = a[r] + bs[r];
        }
    }
}

extern "C" void kernel_launch(void* const* d_in, const int* in_sizes, int n_in,
                              void* d_out, int out_size, void* d_ws, size_t ws_size,
                              hipStream_t stream) {
    const float* x      = (const float*)d_in[0];
    const float* w_qkv  = (const float*)d_in[1];
    const float* b_qkv  = (const float*)d_in[2];
    const float* w_attn = (const float*)d_in[3];
    const float* b_attn = (const float*)d_in[4];
    const float* w_out  = (const float*)d_in[5];
    const float* b_out  = (const float*)d_in[6];
    const float* krh    = (const float*)d_in[7];
    const float* krw    = (const float*)d_in[8];

    char* ws = (char*)d_ws;
    _Float16* xbT  = (_Float16*)(ws);                   // 2 MB
    _Float16* wqb  = (_Float16*)(ws + 2097152);         // 384 KB
    _Float16* wab  = (_Float16*)(ws + 2490368);         // 128 KB
    _Float16* wob  = (_Float16*)(ws + 2621440);         // 128 KB
    _Float16* wrel = (_Float16*)(ws + 2752512);         // 8 KB  (128x32 f16)
    _Float16* qb   = (_Float16*)(ws + 2760704);         // 2 MB
    _Float16* kb   = (_Float16*)(ws + 4857856);         // 2 MB
    _Float16* vt   = (_Float16*)(ws + 6955008);         // 2 MB
    _Float16* attnT= (_Float16*)(ws + 9052160);         // 2 MB
    float* out = (float*)d_out;

    k_prep<<<dim3(896), dim3(256), 0, stream>>>(x, w_qkv, w_attn, w_out, krh, krw,
                                                xbT, wqb, wab, wob, wrel);
    k_qkv <<<dim3(768), dim3(256), 0, stream>>>(xbT, wqb, b_qkv, qb, kb, vt);
    k_attn<<<dim3(2048), dim3(256), 0, stream>>>(qb, kb, vt, wrel, attnT);
    k_out <<<dim3(512), dim3(256), 0, stream>>>(xbT, attnT, wob, wab, b_out, b_attn, out);
}